// Round 7
// baseline (851.555 us; speedup 1.0000x reference)
//
#include <hip/hip_runtime.h>
#include <float.h>
#include <math.h>

// VQ nearest-codebook: z_e (64,256,32,32) fp32 NCHW, codebook (512,256) fp32.
// token t = n*1024 + hw; feature d at z_e[n*262144 + d*1024 + hw].
// d_out: [0,65536) = q as float; [65536,...) = z_q fp32 NCHW.
//
// Ref model: scan approximates m = x.w - 0.5|w|^2; top candidates per token;
// if the approx gap > MARGIN the argmax is final; else replicate the np fp32
// quantized distance (xsq pairwise, fp64 dot -> fp32) tie->low k.
//
// Round-7 changes (R6 lesson: TPB=32's 128B segments doubled HBM traffic;
// R5 lesson: 64KB x-LDS caps at 2 blocks/CU):
//  * 2-term scan m^ = xh*wh + xh*wl (drop xl*wh): differential error
//    xl.(wi-wj) ~ 2.8e-5 RMS -> MARGIN widened 2.5e-4 -> 1e-3 (~35 sigma).
//    x staged hi-only: 32KB LDS. MFMA 192->128/wave.
//  * top-4 cap unsafe at 1e-3 -> per-token merge is TOP-8 (P(9 in window)
//    ~4e-10); per-lane/per-wave top-4 unchanged (lane covers 64 codes).
//  * z_q stage in 2 half-dim rounds (64 rows x 132 fl, pitch class == the
//    proven conflict-free 1040): 33.8KB.
//  * LDS total ~36KB -> 4 blocks/CU at TPB=64 (256B segments everywhere).
//  * Exact-np adjudication path unchanged (worklist, wave-parallel).

#define KCODES 512
#define DDIM   256
#define HWSZ   1024
#define TTOK   65536
#define TPB    64             // tokens per block
#define NBLK   (TTOK / TPB)   // 1024
#define NCHUNK 16             // k-chunks of 16 dims
#define MARGIN 1.0e-3f

// LDS map (bytes): [0, 33792) reuse region:
//   phase A: x hi fragments [mt:2][c:16][lane:64][16B] = 32768
//   phase B: candm 4KB @0, candi 4KB @4096, wl @8192..12560
//   phase C: z_q row stage, 64 rows x 132 floats (528B pitch) = 33792
// [33792, 35840): 0.5*wsq (512 floats)
// [35840, 36096): bkArr (64 ints)
#define HW_OFF 33792
#define BK_OFF 35840
#define LDS_SZ 36096
#define ZQ_PITCH 528          // bytes per staged row (132 floats, 16B aligned)

typedef short bf16x8 __attribute__((ext_vector_type(8)));   // 8 bf16 (4 VGPRs)
typedef float f32x16 __attribute__((ext_vector_type(16)));
typedef float f32x4  __attribute__((ext_vector_type(4)));

__device__ inline unsigned short bf16rne(float x) {
    union { float f; unsigned u; } a; a.f = x;
    unsigned r = a.u + (0x7fffu + ((a.u >> 16) & 1u));
    return (unsigned short)(r >> 16);
}
__device__ inline float bf16tof(unsigned short h) {
    union { unsigned u; float f; } b; b.u = ((unsigned)h) << 16; return b.f;
}

// branchless sorted-descending top-4 insert, strict > (ties keep incumbent)
__device__ __forceinline__ void top4_insert(float m, int c, float fb[4], int fi[4]) {
    #pragma unroll
    for (int l = 0; l < 4; ++l) {
        const bool s = m > fb[l];
        const float nm = s ? fb[l] : m;
        const int   nc = s ? fi[l] : c;
        fb[l] = s ? m : fb[l];
        fi[l] = s ? c : fi[l];
        m = nm; c = nc;
    }
}
// branchless sorted-descending top-8 insert
__device__ __forceinline__ void top8_insert(float m, int c, float fb[8], int fi[8]) {
    #pragma unroll
    for (int l = 0; l < 8; ++l) {
        const bool s = m > fb[l];
        const float nm = s ? fb[l] : m;
        const int   nc = s ? fi[l] : c;
        fb[l] = s ? m : fb[l];
        fi[l] = s ? c : fi[l];
        m = nm; c = nc;
    }
}

// ---------------------------------------------- fused w pack + wsq (np) ----
// ws_w layout: [chunk c:16][part p:2][tile:16][lane:64][16B]  (512 KiB)
// element: code = tile*32 + (lane&31), d = c*16 + (lane>>5)*8 + j
// Blocks 0..31 also compute wsq (16 codes each, 16 lanes/code, exact np
// pairwise order: stripe fold + shfl butterfly).
__global__ __launch_bounds__(256) void vq_prep(const float* __restrict__ cb,
                                               unsigned char* __restrict__ wsw,
                                               float* __restrict__ wsq) {
    const int tid = threadIdx.x;
    const int gid = blockIdx.x * 256 + tid;           // 16384 total
    {
        const int k = gid >> 5, o = gid & 31;
        const int d0 = o * 8, c = o >> 1, half = o & 1;
        unsigned hi[4], lo[4];
        #pragma unroll
        for (int jj = 0; jj < 4; ++jj) {
            float v0 = cb[k * DDIM + d0 + 2 * jj];
            float v1 = cb[k * DDIM + d0 + 2 * jj + 1];
            unsigned short h0 = bf16rne(v0), h1 = bf16rne(v1);
            unsigned short l0 = bf16rne(v0 - bf16tof(h0));
            unsigned short l1 = bf16rne(v1 - bf16tof(h1));
            hi[jj] = (unsigned)h0 | ((unsigned)h1 << 16);
            lo[jj] = (unsigned)l0 | ((unsigned)l1 << 16);
        }
        const int tile = k >> 5, lane2 = (k & 31) + 32 * half;
        *(uint4*)(wsw + ((size_t)((c * 2 + 0) * 16 + tile) * 1024) + lane2 * 16) = make_uint4(hi[0], hi[1], hi[2], hi[3]);
        *(uint4*)(wsw + ((size_t)((c * 2 + 1) * 16 + tile) * 1024) + lane2 * 16) = make_uint4(lo[0], lo[1], lo[2], lo[3]);
    }
    if (blockIdx.x < 32) {
        const int k = blockIdx.x * 16 + (tid >> 4);
        const int s = tid & 15, h2 = s >> 3, j2 = s & 7;
        const float* p = cb + (size_t)k * DDIM + h2 * 128 + j2;
        float v[16];
        #pragma unroll
        for (int i = 0; i < 16; ++i) v[i] = p[i * 8];
        float rr;
        {
#pragma clang fp contract(off)
            rr = v[0] * v[0];
            #pragma unroll
            for (int i = 1; i < 16; ++i) { float sq = v[i] * v[i]; rr = rr + sq; }
        }
        float t = rr;
        t = t + __shfl_xor(t, 1);
        t = t + __shfl_xor(t, 2);
        t = t + __shfl_xor(t, 4);
        t = t + __shfl_xor(t, 8);
        if (s == 0) wsq[k] = t;
    }
}

// ---------------------------------------------------------------- main -----
// 1024 blocks x 512 threads (8 waves). Block = 64 tokens x 512 codes.
// Wave wv: token tile mt = wv&1 (32 tokens), code quarter qc = wv>>1
// (128 codes as 2 pairs of 32-code tiles).
__global__ __launch_bounds__(512, 8) void vq_main(const float* __restrict__ z_e,
                                                  const float* __restrict__ cb,
                                                  const float* __restrict__ wsq,
                                                  const unsigned char* __restrict__ wsw,
                                                  float* __restrict__ out) {
    __shared__ __align__(16) unsigned char lds[LDS_SZ];

    const int tid = threadIdx.x;
    const int wv = tid >> 6, lane = tid & 63;
    const int tbase = blockIdx.x * TPB;
    const int n = tbase >> 10, hw0 = tbase & (HWSZ - 1);
    const float* zb = z_e + (size_t)n * (DDIM * HWSZ) + hw0;

    // ---- stage x -> LDS (bf16 HI only, fragment-packed, b128 writes) ----
    {
        const int tok = tid & 63, g = tid >> 6;     // 8 threads per token
        const int mtS = tok >> 5;
        const int lbase = (tok & 31) * 16;
        #pragma unroll
        for (int o = 0; o < 4; ++o) {
            const int d0 = g * 32 + o * 8;
            float v[8];
            #pragma unroll
            for (int j = 0; j < 8; ++j) v[j] = zb[(size_t)(d0 + j) * HWSZ + tok];
            unsigned hi[4];
            #pragma unroll
            for (int jj = 0; jj < 4; ++jj) {
                unsigned short h0 = bf16rne(v[2 * jj]), h1 = bf16rne(v[2 * jj + 1]);
                hi[jj] = (unsigned)h0 | ((unsigned)h1 << 16);
            }
            const int c = d0 >> 4;
            const int off2 = lbase + 512 * ((d0 >> 3) & 1);
            *(uint4*)(lds + (mtS * 16 + c) * 1024 + off2) = make_uint4(hi[0], hi[1], hi[2], hi[3]);
        }
    }
    // ---- stage 0.5*wsq -> LDS (2KB, broadcast-read in the fold) ----
    ((float*)(lds + HW_OFF))[tid] = 0.5f * wsq[tid];

    __syncthreads();

    // ---- K-loop: 2 pairs of 32-code tiles, 2-term scan ----
    const int qc = wv >> 1;             // code quarter: codes [qc*128, +128)
    const int mt = wv & 1;              // token tile: tokens [mt*32, +32)
    const int hh = lane >> 5;           // which 16-row half of each 32-code tile
    const float* hwsqL = (const float*)(lds + HW_OFF);

    #define LDW(c, p, t)   (*(const bf16x8*)(wsw + ((size_t)(((c) * 2 + (p)) * 16 + (t)) * 1024) + lane * 16))
    #define LDA(mm, c)     (*(const bf16x8*)(lds + ((mm) * 16 + (c)) * 1024 + lane * 16))

    float fb[4] = {-FLT_MAX, -FLT_MAX, -FLT_MAX, -FLT_MAX};
    int   fi[4] = {KCODES, KCODES, KCODES, KCODES};

    #pragma unroll
    for (int pr = 0; pr < 2; ++pr) {
        const int ct0 = qc * 4 + 2 * pr;
        f32x16 a0, a1;
        #pragma unroll
        for (int r = 0; r < 16; ++r) { a0[r] = 0.f; a1[r] = 0.f; }
        bf16x8 Xc[2], Wc[2][4];
        Xc[0] = LDA(mt, 0);
        Wc[0][0] = LDW(0, 0, ct0); Wc[0][1] = LDW(0, 1, ct0);
        Wc[0][2] = LDW(0, 0, ct0 + 1); Wc[0][3] = LDW(0, 1, ct0 + 1);
        #pragma unroll
        for (int c = 0; c < NCHUNK; ++c) {
            const int cur = c & 1, nxt = cur ^ 1;
            if (c + 1 < NCHUNK) {
                Xc[nxt] = LDA(mt, c + 1);
                Wc[nxt][0] = LDW(c + 1, 0, ct0); Wc[nxt][1] = LDW(c + 1, 1, ct0);
                Wc[nxt][2] = LDW(c + 1, 0, ct0 + 1); Wc[nxt][3] = LDW(c + 1, 1, ct0 + 1);
            }
            // m^ = xh*wh + xh*wl  (A=w / B=x)
            a0 = __builtin_amdgcn_mfma_f32_32x32x16_bf16(Wc[cur][0], Xc[cur], a0, 0, 0, 0);
            a1 = __builtin_amdgcn_mfma_f32_32x32x16_bf16(Wc[cur][2], Xc[cur], a1, 0, 0, 0);
            a0 = __builtin_amdgcn_mfma_f32_32x32x16_bf16(Wc[cur][1], Xc[cur], a0, 0, 0, 0);
            a1 = __builtin_amdgcn_mfma_f32_32x32x16_bf16(Wc[cur][3], Xc[cur], a1, 0, 0, 0);
        }
        // C layout (32x32x16): col = lane&31 = token, row = (reg&3)+8*(reg>>2)+4*hh = code%32
        #pragma unroll
        for (int rq = 0; rq < 4; ++rq) {
            const f32x4 h40 = *(const f32x4*)(hwsqL + ct0 * 32 + rq * 8 + 4 * hh);
            const f32x4 h41 = *(const f32x4*)(hwsqL + (ct0 + 1) * 32 + rq * 8 + 4 * hh);
            #pragma unroll
            for (int rr = 0; rr < 4; ++rr) {
                top4_insert(a0[rq * 4 + rr] - h40[rr], ct0 * 32 + rr + 8 * rq + 4 * hh, fb, fi);
                top4_insert(a1[rq * 4 + rr] - h41[rr], (ct0 + 1) * 32 + rr + 8 * rq + 4 * hh, fb, fi);
            }
        }
    }

    // ---- pair merge: lane <-> lane^32 (two 16-row halves of same token) ----
    {
        float sb[4]; int si[4];
        #pragma unroll
        for (int c = 0; c < 4; ++c) { sb[c] = __shfl_xor(fb[c], 32); si[c] = __shfl_xor(fi[c], 32); }
        #pragma unroll
        for (int c = 0; c < 4; ++c) top4_insert(sb[c], si[c], fb, fi);
    }

    // ---- publish per-wave top-4, merge across code quarters (top-8) ----
    __syncthreads();                    // all LDS x reads done; reuse region
    float* candm = (float*)lds;                 // 1024 floats  [qc][tok][4]
    int*   candi = (int*)(lds + 4096);          // 1024 ints
    int*   wlCnt = (int*)(lds + 8192);
    int*   wlTok = (int*)(lds + 8208);          // 64 ints
    int*   wlGi  = (int*)(lds + 8464);          // 64*8 ints
    float* wlG   = (float*)(lds + 10512);       // 64*8 floats
    int*   bkArr = (int*)(lds + BK_OFF);        // 64 ints
    if (lane < 32) {
        const int slot = (qc * 64 + mt * 32 + lane) * 4;
        #pragma unroll
        for (int c = 0; c < 4; ++c) { candm[slot + c] = fb[c]; candi[slot + c] = fi[c]; }
    }
    if (tid == 0) *wlCnt = 0;
    __syncthreads();

    if (tid < TPB) {
        float g[8]; int gi[8];
        #pragma unroll
        for (int c = 0; c < 8; ++c) { g[c] = -FLT_MAX; gi[c] = KCODES; }
        #pragma unroll
        for (int q4 = 0; q4 < 4; ++q4) {
            const int slot = (q4 * 64 + tid) * 4;
            #pragma unroll
            for (int c = 0; c < 4; ++c) top8_insert(candm[slot + c], candi[slot + c], g, gi);
        }
        if (g[0] - g[1] > MARGIN) {
            // gap >> 2-term error window: argmax final
            out[tbase + tid] = (float)gi[0];
            bkArr[tid] = gi[0];
        } else {
            const int slot = atomicAdd(wlCnt, 1);
            wlTok[slot] = tid;
            #pragma unroll
            for (int c = 0; c < 8; ++c) { wlGi[slot * 8 + c] = gi[c]; wlG[slot * 8 + c] = g[c]; }
        }
    }
    __syncthreads();

    // ---- adjudication: all 8 waves round-robin the worklist; one wave/item ----
    {
        const int nIt = *wlCnt;
        for (int it = wv; it < nIt; it += 8) {
            const int tok = wlTok[it];
            const float g0 = wlG[it * 8];
            const float* xa = zb + tok;

            // xsq: bitwise np pairwise. Lane s<16 (s = h*8+j) runs stripe j of
            // half h as a serial 16-term fold; butterfly reproduces the exact
            // pairwise combine ((r0+r1)+(r2+r3))+((r4+r5)+(r6+r7)), sh0+sh1.
            float xsq;
            {
                const int h2 = (lane >> 3) & 1, j2 = lane & 7;
                float v[16];
                if (lane < 16) {
                    #pragma unroll
                    for (int i = 0; i < 16; ++i)
                        v[i] = xa[(size_t)(h2 * 128 + i * 8 + j2) * HWSZ];
                } else {
                    #pragma unroll
                    for (int i = 0; i < 16; ++i) v[i] = 0.f;
                }
                float rr;
                {
#pragma clang fp contract(off)
                    rr = v[0] * v[0];
                    #pragma unroll
                    for (int i = 1; i < 16; ++i) { float sq = v[i] * v[i]; rr = rr + sq; }
                }
                float t = rr;
                t = t + __shfl_xor(t, 1);
                t = t + __shfl_xor(t, 2);
                t = t + __shfl_xor(t, 4);
                t = t + __shfl_xor(t, 8);
                xsq = __shfl(t, 0);
            }

            // x column into regs for the dots (lane d0 = lane, +64 strides)
            double xv[4];
            #pragma unroll
            for (int i = 0; i < 4; ++i)
                xv[i] = (double)xa[(size_t)(lane + 64 * i) * HWSZ];

            float bestd = FLT_MAX; int bestk = KCODES;
            for (int c = 0; c < 8; ++c) {
                const float gc = wlG[it * 8 + c];
                if (c > 0 && g0 - gc > MARGIN) break;   // wave-uniform
                const int idx = wlGi[it * 8 + c];
                const float* wr = cb + (size_t)idx * DDIM;
                double A = 0.0;
                #pragma unroll
                for (int i = 0; i < 4; ++i)
                    A = fma((double)wr[lane + 64 * i], xv[i], A);
                // fp64 butterfly reduce (order-free: 29 spare bits vs fp32)
                A = A + __shfl_xor(A, 1);
                A = A + __shfl_xor(A, 2);
                A = A + __shfl_xor(A, 4);
                A = A + __shfl_xor(A, 8);
                A = A + __shfl_xor(A, 16);
                A = A + __shfl_xor(A, 32);
                float dist;
                {
#pragma clang fp contract(off)
                    const float xw = (float)A;
                    const float t1 = xsq - 2.0f * xw;
                    dist = t1 + wsq[idx];
                }
                if (dist < bestd || (dist == bestd && idx < bestk)) { bestd = dist; bestk = idx; }
            }
            if (lane == 0) {
                out[tbase + tok] = (float)bestk;
                bkArr[tok] = bestk;
            }
        }
    }

    // ---- z_q: 2 rounds of (stage 64 rows x 128 dims -> write coalesced) ----
    #pragma unroll
    for (int r = 0; r < 2; ++r) {
        __syncthreads();                // reuse region free / prev round done
        {
            #pragma unroll
            for (int rr = 0; rr < 8; ++rr) {
                const int row = wv * 8 + rr;
                const int bk = bkArr[row];                        // wave-uniform
                const float2 vv = *(const float2*)(cb + (size_t)bk * DDIM + r * 128 + lane * 2);
                *(float2*)(lds + row * ZQ_PITCH + lane * 8) = vv;
            }
        }
        __syncthreads();
        {
            const int tk = tid & 63, s = tid >> 6;     // s = 0..7, 16 dims each
            float* zq = out + TTOK + (size_t)n * (DDIM * HWSZ) + hw0 + tk;
            #pragma unroll
            for (int i = 0; i < 16; i += 4) {
                const f32x4 v = *(const f32x4*)(lds + tk * ZQ_PITCH + (s * 16 + i) * 4);
                #pragma unroll
                for (int j = 0; j < 4; ++j)
                    zq[(size_t)(r * 128 + s * 16 + i + j) * HWSZ] = v[j];
            }
        }
    }
}

// --------------------------------------------------------------- launch ----
extern "C" void kernel_launch(void* const* d_in, const int* in_sizes, int n_in,
                              void* d_out, int out_size, void* d_ws, size_t ws_size,
                              hipStream_t stream) {
    const float* z_e = (const float*)d_in[0];
    const float* cb  = (const float*)d_in[1];
    float* out = (float*)d_out;
    float* wsq = (float*)d_ws;                              // 2 KiB
    unsigned char* wsw = (unsigned char*)d_ws + 2048;       // 512 KiB fragment-packed w

    vq_prep<<<64, 256, 0, stream>>>(cb, wsw, wsq);
    vq_main<<<NBLK, 512, 0, stream>>>(z_e, cb, wsq, wsw, out);
}

// Round 8
// 648.417 us; speedup vs baseline: 1.3133x; 1.3133x over previous
//
#include <hip/hip_runtime.h>
#include <float.h>
#include <math.h>

// VQ nearest-codebook: z_e (64,256,32,32) fp32 NCHW, codebook (512,256) fp32.
// token t = n*1024 + hw; feature d at z_e[n*262144 + d*1024 + hw].
// d_out: [0,65536) = q as float; [65536,...) = z_q fp32 NCHW.
//
// Ref model: scan approximates m = x.w - 0.5|w|^2; top candidates per token;
// if the approx gap > MARGIN the argmax is final; else replicate the np fp32
// quantized distance (xsq pairwise, fp64 dot -> fp32) tie->low k.
//
// Round-8 changes (R7 lesson: (512,8) caps the UNIFIED reg file at 64/lane;
// R7's 2-tile + double-buffered K-loop needed ~80 live regs -> scratch spill,
// 2.2GB of scratch writes, 8x slowdown. Occupancy quantum is 64/128/256, so
// >2 blocks/CU REQUIRES fitting 64 regs):
//  * K-loop: ONE 16-reg accumulator tile at a time (4 sequential tiles/wave),
//    NO register double-buffer -- TLP at 8 waves/SIMD hides latency. Live set
//    ~50 regs < 64. X re-read from LDS per tile (negligible).
//  * Everything else identical to R7 (verified correct): 2-term scan hi-only
//    staging (32KB), MARGIN 1e-3, top-8 merge, worklist adjudication,
//    2-round z_q staging, TPB=64 (256B segments), LDS ~36KB -> 4 blocks/CU.

#define KCODES 512
#define DDIM   256
#define HWSZ   1024
#define TTOK   65536
#define TPB    64             // tokens per block
#define NBLK   (TTOK / TPB)   // 1024
#define NCHUNK 16             // k-chunks of 16 dims
#define MARGIN 1.0e-3f

// LDS map (bytes): [0, 33792) reuse region:
//   phase A: x hi fragments [mt:2][c:16][lane:64][16B] = 32768
//   phase B: candm 4KB @0, candi 4KB @4096, wl @8192..12560
//   phase C: z_q row stage, 64 rows x 132 floats (528B pitch) = 33792
// [33792, 35840): 0.5*wsq (512 floats)
// [35840, 36096): bkArr (64 ints)
#define HW_OFF 33792
#define BK_OFF 35840
#define LDS_SZ 36096
#define ZQ_PITCH 528          // bytes per staged row (132 floats, 16B aligned)

typedef short bf16x8 __attribute__((ext_vector_type(8)));   // 8 bf16 (4 VGPRs)
typedef float f32x16 __attribute__((ext_vector_type(16)));
typedef float f32x4  __attribute__((ext_vector_type(4)));

__device__ inline unsigned short bf16rne(float x) {
    union { float f; unsigned u; } a; a.f = x;
    unsigned r = a.u + (0x7fffu + ((a.u >> 16) & 1u));
    return (unsigned short)(r >> 16);
}
__device__ inline float bf16tof(unsigned short h) {
    union { unsigned u; float f; } b; b.u = ((unsigned)h) << 16; return b.f;
}

// branchless sorted-descending top-4 insert, strict > (ties keep incumbent)
__device__ __forceinline__ void top4_insert(float m, int c, float fb[4], int fi[4]) {
    #pragma unroll
    for (int l = 0; l < 4; ++l) {
        const bool s = m > fb[l];
        const float nm = s ? fb[l] : m;
        const int   nc = s ? fi[l] : c;
        fb[l] = s ? m : fb[l];
        fi[l] = s ? c : fi[l];
        m = nm; c = nc;
    }
}
// branchless sorted-descending top-8 insert
__device__ __forceinline__ void top8_insert(float m, int c, float fb[8], int fi[8]) {
    #pragma unroll
    for (int l = 0; l < 8; ++l) {
        const bool s = m > fb[l];
        const float nm = s ? fb[l] : m;
        const int   nc = s ? fi[l] : c;
        fb[l] = s ? m : fb[l];
        fi[l] = s ? c : fi[l];
        m = nm; c = nc;
    }
}

// ---------------------------------------------- fused w pack + wsq (np) ----
// ws_w layout: [chunk c:16][part p:2][tile:16][lane:64][16B]  (512 KiB)
// element: code = tile*32 + (lane&31), d = c*16 + (lane>>5)*8 + j
// Blocks 0..31 also compute wsq (16 codes each, 16 lanes/code, exact np
// pairwise order: stripe fold + shfl butterfly).
__global__ __launch_bounds__(256) void vq_prep(const float* __restrict__ cb,
                                               unsigned char* __restrict__ wsw,
                                               float* __restrict__ wsq) {
    const int tid = threadIdx.x;
    const int gid = blockIdx.x * 256 + tid;           // 16384 total
    {
        const int k = gid >> 5, o = gid & 31;
        const int d0 = o * 8, c = o >> 1, half = o & 1;
        unsigned hi[4], lo[4];
        #pragma unroll
        for (int jj = 0; jj < 4; ++jj) {
            float v0 = cb[k * DDIM + d0 + 2 * jj];
            float v1 = cb[k * DDIM + d0 + 2 * jj + 1];
            unsigned short h0 = bf16rne(v0), h1 = bf16rne(v1);
            unsigned short l0 = bf16rne(v0 - bf16tof(h0));
            unsigned short l1 = bf16rne(v1 - bf16tof(h1));
            hi[jj] = (unsigned)h0 | ((unsigned)h1 << 16);
            lo[jj] = (unsigned)l0 | ((unsigned)l1 << 16);
        }
        const int tile = k >> 5, lane2 = (k & 31) + 32 * half;
        *(uint4*)(wsw + ((size_t)((c * 2 + 0) * 16 + tile) * 1024) + lane2 * 16) = make_uint4(hi[0], hi[1], hi[2], hi[3]);
        *(uint4*)(wsw + ((size_t)((c * 2 + 1) * 16 + tile) * 1024) + lane2 * 16) = make_uint4(lo[0], lo[1], lo[2], lo[3]);
    }
    if (blockIdx.x < 32) {
        const int k = blockIdx.x * 16 + (tid >> 4);
        const int s = tid & 15, h2 = s >> 3, j2 = s & 7;
        const float* p = cb + (size_t)k * DDIM + h2 * 128 + j2;
        float v[16];
        #pragma unroll
        for (int i = 0; i < 16; ++i) v[i] = p[i * 8];
        float rr;
        {
#pragma clang fp contract(off)
            rr = v[0] * v[0];
            #pragma unroll
            for (int i = 1; i < 16; ++i) { float sq = v[i] * v[i]; rr = rr + sq; }
        }
        float t = rr;
        t = t + __shfl_xor(t, 1);
        t = t + __shfl_xor(t, 2);
        t = t + __shfl_xor(t, 4);
        t = t + __shfl_xor(t, 8);
        if (s == 0) wsq[k] = t;
    }
}

// ---------------------------------------------------------------- main -----
// 1024 blocks x 512 threads (8 waves). Block = 64 tokens x 512 codes.
// Wave wv: token tile mt = wv&1 (32 tokens), code quarter qc = wv>>1
// (128 codes as 4 sequential 32-code tiles, ONE 16-reg accumulator at a time).
__global__ __launch_bounds__(512, 8) void vq_main(const float* __restrict__ z_e,
                                                  const float* __restrict__ cb,
                                                  const float* __restrict__ wsq,
                                                  const unsigned char* __restrict__ wsw,
                                                  float* __restrict__ out) {
    __shared__ __align__(16) unsigned char lds[LDS_SZ];

    const int tid = threadIdx.x;
    const int wv = tid >> 6, lane = tid & 63;
    const int tbase = blockIdx.x * TPB;
    const int n = tbase >> 10, hw0 = tbase & (HWSZ - 1);
    const float* zb = z_e + (size_t)n * (DDIM * HWSZ) + hw0;

    // ---- stage x -> LDS (bf16 HI only, fragment-packed, b128 writes) ----
    {
        const int tok = tid & 63, g = tid >> 6;     // 8 threads per token
        const int mtS = tok >> 5;
        const int lbase = (tok & 31) * 16;
        #pragma unroll
        for (int o = 0; o < 4; ++o) {
            const int d0 = g * 32 + o * 8;
            float v[8];
            #pragma unroll
            for (int j = 0; j < 8; ++j) v[j] = zb[(size_t)(d0 + j) * HWSZ + tok];
            unsigned hi[4];
            #pragma unroll
            for (int jj = 0; jj < 4; ++jj) {
                unsigned short h0 = bf16rne(v[2 * jj]), h1 = bf16rne(v[2 * jj + 1]);
                hi[jj] = (unsigned)h0 | ((unsigned)h1 << 16);
            }
            const int c = d0 >> 4;
            const int off2 = lbase + 512 * ((d0 >> 3) & 1);
            *(uint4*)(lds + (mtS * 16 + c) * 1024 + off2) = make_uint4(hi[0], hi[1], hi[2], hi[3]);
        }
    }
    // ---- stage 0.5*wsq -> LDS (2KB, broadcast-read in the fold) ----
    ((float*)(lds + HW_OFF))[tid] = 0.5f * wsq[tid];

    __syncthreads();

    // ---- K-loop: 4 sequential 32-code tiles, 2-term scan, 1 acc tile ----
    const int qc = wv >> 1;             // code quarter: codes [qc*128, +128)
    const int mt = wv & 1;              // token tile: tokens [mt*32, +32)
    const int hh = lane >> 5;           // which 16-row half of each 32-code tile
    const float* hwsqL = (const float*)(lds + HW_OFF);

    #define LDW(c, p, t)   (*(const bf16x8*)(wsw + ((size_t)(((c) * 2 + (p)) * 16 + (t)) * 1024) + lane * 16))
    #define LDA(mm, c)     (*(const bf16x8*)(lds + ((mm) * 16 + (c)) * 1024 + lane * 16))

    float fb[4] = {-FLT_MAX, -FLT_MAX, -FLT_MAX, -FLT_MAX};
    int   fi[4] = {KCODES, KCODES, KCODES, KCODES};

    #pragma unroll
    for (int ti = 0; ti < 4; ++ti) {
        const int ct = qc * 4 + ti;
        f32x16 a;
        #pragma unroll
        for (int r = 0; r < 16; ++r) a[r] = 0.f;
        #pragma unroll
        for (int c = 0; c < NCHUNK; ++c) {
            const bf16x8 X  = LDA(mt, c);
            const bf16x8 Wh = LDW(c, 0, ct);
            const bf16x8 Wl = LDW(c, 1, ct);
            // m^ = xh*wh + xh*wl  (A=w / B=x)
            a = __builtin_amdgcn_mfma_f32_32x32x16_bf16(Wh, X, a, 0, 0, 0);
            a = __builtin_amdgcn_mfma_f32_32x32x16_bf16(Wl, X, a, 0, 0, 0);
        }
        // C layout (32x32x16): col = lane&31 = token, row = (reg&3)+8*(reg>>2)+4*hh = code%32
        #pragma unroll
        for (int rq = 0; rq < 4; ++rq) {
            const f32x4 h4 = *(const f32x4*)(hwsqL + ct * 32 + rq * 8 + 4 * hh);
            #pragma unroll
            for (int rr = 0; rr < 4; ++rr)
                top4_insert(a[rq * 4 + rr] - h4[rr], ct * 32 + rr + 8 * rq + 4 * hh, fb, fi);
        }
    }

    // ---- pair merge: lane <-> lane^32 (two 16-row halves of same token) ----
    {
        float sb[4]; int si[4];
        #pragma unroll
        for (int c = 0; c < 4; ++c) { sb[c] = __shfl_xor(fb[c], 32); si[c] = __shfl_xor(fi[c], 32); }
        #pragma unroll
        for (int c = 0; c < 4; ++c) top4_insert(sb[c], si[c], fb, fi);
    }

    // ---- publish per-wave top-4, merge across code quarters (top-8) ----
    __syncthreads();                    // all LDS x reads done; reuse region
    float* candm = (float*)lds;                 // 1024 floats  [qc][tok][4]
    int*   candi = (int*)(lds + 4096);          // 1024 ints
    int*   wlCnt = (int*)(lds + 8192);
    int*   wlTok = (int*)(lds + 8208);          // 64 ints
    int*   wlGi  = (int*)(lds + 8464);          // 64*8 ints
    float* wlG   = (float*)(lds + 10512);       // 64*8 floats
    int*   bkArr = (int*)(lds + BK_OFF);        // 64 ints
    if (lane < 32) {
        const int slot = (qc * 64 + mt * 32 + lane) * 4;
        #pragma unroll
        for (int c = 0; c < 4; ++c) { candm[slot + c] = fb[c]; candi[slot + c] = fi[c]; }
    }
    if (tid == 0) *wlCnt = 0;
    __syncthreads();

    if (tid < TPB) {
        float g[8]; int gi[8];
        #pragma unroll
        for (int c = 0; c < 8; ++c) { g[c] = -FLT_MAX; gi[c] = KCODES; }
        #pragma unroll
        for (int q4 = 0; q4 < 4; ++q4) {
            const int slot = (q4 * 64 + tid) * 4;
            #pragma unroll
            for (int c = 0; c < 4; ++c) top8_insert(candm[slot + c], candi[slot + c], g, gi);
        }
        if (g[0] - g[1] > MARGIN) {
            // gap >> 2-term error window: argmax final
            out[tbase + tid] = (float)gi[0];
            bkArr[tid] = gi[0];
        } else {
            const int slot = atomicAdd(wlCnt, 1);
            wlTok[slot] = tid;
            #pragma unroll
            for (int c = 0; c < 8; ++c) { wlGi[slot * 8 + c] = gi[c]; wlG[slot * 8 + c] = g[c]; }
        }
    }
    __syncthreads();

    // ---- adjudication: all 8 waves round-robin the worklist; one wave/item ----
    {
        const int nIt = *wlCnt;
        for (int it = wv; it < nIt; it += 8) {
            const int tok = wlTok[it];
            const float g0 = wlG[it * 8];
            const float* xa = zb + tok;

            // xsq: bitwise np pairwise. Lane s<16 (s = h*8+j) runs stripe j of
            // half h as a serial 16-term fold; butterfly reproduces the exact
            // pairwise combine ((r0+r1)+(r2+r3))+((r4+r5)+(r6+r7)), sh0+sh1.
            float xsq;
            {
                const int h2 = (lane >> 3) & 1, j2 = lane & 7;
                float v[16];
                if (lane < 16) {
                    #pragma unroll
                    for (int i = 0; i < 16; ++i)
                        v[i] = xa[(size_t)(h2 * 128 + i * 8 + j2) * HWSZ];
                } else {
                    #pragma unroll
                    for (int i = 0; i < 16; ++i) v[i] = 0.f;
                }
                float rr;
                {
#pragma clang fp contract(off)
                    rr = v[0] * v[0];
                    #pragma unroll
                    for (int i = 1; i < 16; ++i) { float sq = v[i] * v[i]; rr = rr + sq; }
                }
                float t = rr;
                t = t + __shfl_xor(t, 1);
                t = t + __shfl_xor(t, 2);
                t = t + __shfl_xor(t, 4);
                t = t + __shfl_xor(t, 8);
                xsq = __shfl(t, 0);
            }

            // x column into regs for the dots (lane d0 = lane, +64 strides)
            double xv[4];
            #pragma unroll
            for (int i = 0; i < 4; ++i)
                xv[i] = (double)xa[(size_t)(lane + 64 * i) * HWSZ];

            float bestd = FLT_MAX; int bestk = KCODES;
            for (int c = 0; c < 8; ++c) {
                const float gc = wlG[it * 8 + c];
                if (c > 0 && g0 - gc > MARGIN) break;   // wave-uniform
                const int idx = wlGi[it * 8 + c];
                const float* wr = cb + (size_t)idx * DDIM;
                double A = 0.0;
                #pragma unroll
                for (int i = 0; i < 4; ++i)
                    A = fma((double)wr[lane + 64 * i], xv[i], A);
                // fp64 butterfly reduce (order-free: 29 spare bits vs fp32)
                A = A + __shfl_xor(A, 1);
                A = A + __shfl_xor(A, 2);
                A = A + __shfl_xor(A, 4);
                A = A + __shfl_xor(A, 8);
                A = A + __shfl_xor(A, 16);
                A = A + __shfl_xor(A, 32);
                float dist;
                {
#pragma clang fp contract(off)
                    const float xw = (float)A;
                    const float t1 = xsq - 2.0f * xw;
                    dist = t1 + wsq[idx];
                }
                if (dist < bestd || (dist == bestd && idx < bestk)) { bestd = dist; bestk = idx; }
            }
            if (lane == 0) {
                out[tbase + tok] = (float)bestk;
                bkArr[tok] = bestk;
            }
        }
    }

    // ---- z_q: 2 rounds of (stage 64 rows x 128 dims -> write coalesced) ----
    #pragma unroll
    for (int r = 0; r < 2; ++r) {
        __syncthreads();                // reuse region free / prev round done
        {
            #pragma unroll
            for (int rr = 0; rr < 8; ++rr) {
                const int row = wv * 8 + rr;
                const int bk = bkArr[row];                        // wave-uniform
                const float2 vv = *(const float2*)(cb + (size_t)bk * DDIM + r * 128 + lane * 2);
                *(float2*)(lds + row * ZQ_PITCH + lane * 8) = vv;
            }
        }
        __syncthreads();
        {
            const int tk = tid & 63, s = tid >> 6;     // s = 0..7, 16 dims each
            float* zq = out + TTOK + (size_t)n * (DDIM * HWSZ) + hw0 + tk;
            #pragma unroll
            for (int i = 0; i < 16; i += 4) {
                const f32x4 v = *(const f32x4*)(lds + tk * ZQ_PITCH + (s * 16 + i) * 4);
                #pragma unroll
                for (int j = 0; j < 4; ++j)
                    zq[(size_t)(r * 128 + s * 16 + i + j) * HWSZ] = v[j];
            }
        }
    }
}

// --------------------------------------------------------------- launch ----
extern "C" void kernel_launch(void* const* d_in, const int* in_sizes, int n_in,
                              void* d_out, int out_size, void* d_ws, size_t ws_size,
                              hipStream_t stream) {
    const float* z_e = (const float*)d_in[0];
    const float* cb  = (const float*)d_in[1];
    float* out = (float*)d_out;
    float* wsq = (float*)d_ws;                              // 2 KiB
    unsigned char* wsw = (unsigned char*)d_ws + 2048;       // 512 KiB fragment-packed w

    vq_prep<<<64, 256, 0, stream>>>(cb, wsw, wsq);
    vq_main<<<NBLK, 512, 0, stream>>>(z_e, cb, wsq, wsw, out);
}

// Round 9
// 182.515 us; speedup vs baseline: 4.6657x; 3.5527x over previous
//
#include <hip/hip_runtime.h>
#include <float.h>
#include <math.h>

// VQ nearest-codebook: z_e (64,256,32,32) fp32 NCHW, codebook (512,256) fp32.
// token t = n*1024 + hw; feature d at z_e[n*262144 + d*1024 + hw].
// d_out: [0,65536) = q as float; [65536,...) = z_q fp32 NCHW.
//
// Ref model: scan approximates m = x.w - 0.5|w|^2; top candidates per token;
// if the approx gap > MARGIN the argmax is final; else replicate the np fp32
// quantized distance (xsq pairwise, fp64 dot -> fp32) tie->low k.
//
// Round-9 (R7/R8 lesson: forcing 8 waves/EU caps unified regs at 64 ->
// compiler spills GB of scratch; this kernel does NOT fit 64. Revert to the
// proven R5 chassis: (512,4) bounds, 128-reg budget, double-buffered K-loop,
// ZERO spill at 103us) + keep the verified work-reductions from R6-R8:
//  * 2-term scan m^ = xh*wh + xh*wl (MFMA 192->128/wave), MARGIN 1e-3,
//    top-8 global merge (P(9 in window) negligible), hi-only x staging
//    (32KB, half the stage VALU), fused prep, 2-round z_q staging.
//  * LDS 36KB: if the slimmer loop lands <=64 unified regs the HW gives
//    4 blocks/CU for free; prediction does not depend on it.

#define KCODES 512
#define DDIM   256
#define HWSZ   1024
#define TTOK   65536
#define TPB    64             // tokens per block
#define NBLK   (TTOK / TPB)   // 1024
#define NCHUNK 16             // k-chunks of 16 dims
#define MARGIN 1.0e-3f

// LDS map (bytes): [0, 33792) reuse region:
//   phase A: x hi fragments [mt:2][c:16][lane:64][16B] = 32768
//   phase B: candm 4KB @0, candi 4KB @4096, wl @8192..12560
//   phase C: z_q row stage, 64 rows x 132 floats (528B pitch) = 33792
// [33792, 35840): 0.5*wsq (512 floats)
// [35840, 36096): bkArr (64 ints)
#define HW_OFF 33792
#define BK_OFF 35840
#define LDS_SZ 36096
#define ZQ_PITCH 528          // bytes per staged row (132 floats, 16B aligned)

typedef short bf16x8 __attribute__((ext_vector_type(8)));   // 8 bf16 (4 VGPRs)
typedef float f32x16 __attribute__((ext_vector_type(16)));
typedef float f32x4  __attribute__((ext_vector_type(4)));

__device__ inline unsigned short bf16rne(float x) {
    union { float f; unsigned u; } a; a.f = x;
    unsigned r = a.u + (0x7fffu + ((a.u >> 16) & 1u));
    return (unsigned short)(r >> 16);
}
__device__ inline float bf16tof(unsigned short h) {
    union { unsigned u; float f; } b; b.u = ((unsigned)h) << 16; return b.f;
}

// branchless sorted-descending top-4 insert, strict > (ties keep incumbent)
__device__ __forceinline__ void top4_insert(float m, int c, float fb[4], int fi[4]) {
    #pragma unroll
    for (int l = 0; l < 4; ++l) {
        const bool s = m > fb[l];
        const float nm = s ? fb[l] : m;
        const int   nc = s ? fi[l] : c;
        fb[l] = s ? m : fb[l];
        fi[l] = s ? c : fi[l];
        m = nm; c = nc;
    }
}
// branchless sorted-descending top-8 insert
__device__ __forceinline__ void top8_insert(float m, int c, float fb[8], int fi[8]) {
    #pragma unroll
    for (int l = 0; l < 8; ++l) {
        const bool s = m > fb[l];
        const float nm = s ? fb[l] : m;
        const int   nc = s ? fi[l] : c;
        fb[l] = s ? m : fb[l];
        fi[l] = s ? c : fi[l];
        m = nm; c = nc;
    }
}

// ---------------------------------------------- fused w pack + wsq (np) ----
// ws_w layout: [chunk c:16][part p:2][tile:16][lane:64][16B]  (512 KiB)
// element: code = tile*32 + (lane&31), d = c*16 + (lane>>5)*8 + j
// Blocks 0..31 also compute wsq (16 codes each, 16 lanes/code, exact np
// pairwise order: stripe fold + shfl butterfly).
__global__ __launch_bounds__(256) void vq_prep(const float* __restrict__ cb,
                                               unsigned char* __restrict__ wsw,
                                               float* __restrict__ wsq) {
    const int tid = threadIdx.x;
    const int gid = blockIdx.x * 256 + tid;           // 16384 total
    {
        const int k = gid >> 5, o = gid & 31;
        const int d0 = o * 8, c = o >> 1, half = o & 1;
        unsigned hi[4], lo[4];
        #pragma unroll
        for (int jj = 0; jj < 4; ++jj) {
            float v0 = cb[k * DDIM + d0 + 2 * jj];
            float v1 = cb[k * DDIM + d0 + 2 * jj + 1];
            unsigned short h0 = bf16rne(v0), h1 = bf16rne(v1);
            unsigned short l0 = bf16rne(v0 - bf16tof(h0));
            unsigned short l1 = bf16rne(v1 - bf16tof(h1));
            hi[jj] = (unsigned)h0 | ((unsigned)h1 << 16);
            lo[jj] = (unsigned)l0 | ((unsigned)l1 << 16);
        }
        const int tile = k >> 5, lane2 = (k & 31) + 32 * half;
        *(uint4*)(wsw + ((size_t)((c * 2 + 0) * 16 + tile) * 1024) + lane2 * 16) = make_uint4(hi[0], hi[1], hi[2], hi[3]);
        *(uint4*)(wsw + ((size_t)((c * 2 + 1) * 16 + tile) * 1024) + lane2 * 16) = make_uint4(lo[0], lo[1], lo[2], lo[3]);
    }
    if (blockIdx.x < 32) {
        const int k = blockIdx.x * 16 + (tid >> 4);
        const int s = tid & 15, h2 = s >> 3, j2 = s & 7;
        const float* p = cb + (size_t)k * DDIM + h2 * 128 + j2;
        float v[16];
        #pragma unroll
        for (int i = 0; i < 16; ++i) v[i] = p[i * 8];
        float rr;
        {
#pragma clang fp contract(off)
            rr = v[0] * v[0];
            #pragma unroll
            for (int i = 1; i < 16; ++i) { float sq = v[i] * v[i]; rr = rr + sq; }
        }
        float t = rr;
        t = t + __shfl_xor(t, 1);
        t = t + __shfl_xor(t, 2);
        t = t + __shfl_xor(t, 4);
        t = t + __shfl_xor(t, 8);
        if (s == 0) wsq[k] = t;
    }
}

// ---------------------------------------------------------------- main -----
// 1024 blocks x 512 threads (8 waves). Block = 64 tokens x 512 codes.
// Wave wv: token tile mt = wv&1 (32 tokens), code quarter qc = wv>>1
// (128 codes as 2 pairs of 32-code tiles, reg-double-buffered).
__global__ __launch_bounds__(512, 4) void vq_main(const float* __restrict__ z_e,
                                                  const float* __restrict__ cb,
                                                  const float* __restrict__ wsq,
                                                  const unsigned char* __restrict__ wsw,
                                                  float* __restrict__ out) {
    __shared__ __align__(16) unsigned char lds[LDS_SZ];

    const int tid = threadIdx.x;
    const int wv = tid >> 6, lane = tid & 63;
    const int tbase = blockIdx.x * TPB;
    const int n = tbase >> 10, hw0 = tbase & (HWSZ - 1);
    const float* zb = z_e + (size_t)n * (DDIM * HWSZ) + hw0;

    // ---- stage x -> LDS (bf16 HI only, fragment-packed, b128 writes) ----
    {
        const int tok = tid & 63, g = tid >> 6;     // 8 threads per token
        const int mtS = tok >> 5;
        const int lbase = (tok & 31) * 16;
        #pragma unroll
        for (int o = 0; o < 4; ++o) {
            const int d0 = g * 32 + o * 8;
            float v[8];
            #pragma unroll
            for (int j = 0; j < 8; ++j) v[j] = zb[(size_t)(d0 + j) * HWSZ + tok];
            unsigned hi[4];
            #pragma unroll
            for (int jj = 0; jj < 4; ++jj) {
                unsigned short h0 = bf16rne(v[2 * jj]), h1 = bf16rne(v[2 * jj + 1]);
                hi[jj] = (unsigned)h0 | ((unsigned)h1 << 16);
            }
            const int c = d0 >> 4;
            const int off2 = lbase + 512 * ((d0 >> 3) & 1);
            *(uint4*)(lds + (mtS * 16 + c) * 1024 + off2) = make_uint4(hi[0], hi[1], hi[2], hi[3]);
        }
    }
    // ---- stage 0.5*wsq -> LDS (2KB, broadcast-read in the fold) ----
    ((float*)(lds + HW_OFF))[tid] = 0.5f * wsq[tid];

    __syncthreads();

    // ---- K-loop: 2 pairs of 32-code tiles, 2-term scan, double-buffered ----
    const int qc = wv >> 1;             // code quarter: codes [qc*128, +128)
    const int mt = wv & 1;              // token tile: tokens [mt*32, +32)
    const int hh = lane >> 5;           // which 16-row half of each 32-code tile
    const float* hwsqL = (const float*)(lds + HW_OFF);

    #define LDW(c, p, t)   (*(const bf16x8*)(wsw + ((size_t)(((c) * 2 + (p)) * 16 + (t)) * 1024) + lane * 16))
    #define LDA(mm, c)     (*(const bf16x8*)(lds + ((mm) * 16 + (c)) * 1024 + lane * 16))

    float fb[4] = {-FLT_MAX, -FLT_MAX, -FLT_MAX, -FLT_MAX};
    int   fi[4] = {KCODES, KCODES, KCODES, KCODES};

    #pragma unroll
    for (int pr = 0; pr < 2; ++pr) {
        const int ct0 = qc * 4 + 2 * pr;
        f32x16 a0, a1;
        #pragma unroll
        for (int r = 0; r < 16; ++r) { a0[r] = 0.f; a1[r] = 0.f; }
        bf16x8 Xc[2], Wc[2][4];
        Xc[0] = LDA(mt, 0);
        Wc[0][0] = LDW(0, 0, ct0); Wc[0][1] = LDW(0, 1, ct0);
        Wc[0][2] = LDW(0, 0, ct0 + 1); Wc[0][3] = LDW(0, 1, ct0 + 1);
        #pragma unroll
        for (int c = 0; c < NCHUNK; ++c) {
            const int cur = c & 1, nxt = cur ^ 1;
            if (c + 1 < NCHUNK) {
                Xc[nxt] = LDA(mt, c + 1);
                Wc[nxt][0] = LDW(c + 1, 0, ct0); Wc[nxt][1] = LDW(c + 1, 1, ct0);
                Wc[nxt][2] = LDW(c + 1, 0, ct0 + 1); Wc[nxt][3] = LDW(c + 1, 1, ct0 + 1);
            }
            // m^ = xh*wh + xh*wl  (A=w / B=x)
            a0 = __builtin_amdgcn_mfma_f32_32x32x16_bf16(Wc[cur][0], Xc[cur], a0, 0, 0, 0);
            a1 = __builtin_amdgcn_mfma_f32_32x32x16_bf16(Wc[cur][2], Xc[cur], a1, 0, 0, 0);
            a0 = __builtin_amdgcn_mfma_f32_32x32x16_bf16(Wc[cur][1], Xc[cur], a0, 0, 0, 0);
            a1 = __builtin_amdgcn_mfma_f32_32x32x16_bf16(Wc[cur][3], Xc[cur], a1, 0, 0, 0);
        }
        // C layout (32x32x16): col = lane&31 = token, row = (reg&3)+8*(reg>>2)+4*hh = code%32
        #pragma unroll
        for (int rq = 0; rq < 4; ++rq) {
            const f32x4 h40 = *(const f32x4*)(hwsqL + ct0 * 32 + rq * 8 + 4 * hh);
            const f32x4 h41 = *(const f32x4*)(hwsqL + (ct0 + 1) * 32 + rq * 8 + 4 * hh);
            #pragma unroll
            for (int rr = 0; rr < 4; ++rr) {
                top4_insert(a0[rq * 4 + rr] - h40[rr], ct0 * 32 + rr + 8 * rq + 4 * hh, fb, fi);
                top4_insert(a1[rq * 4 + rr] - h41[rr], (ct0 + 1) * 32 + rr + 8 * rq + 4 * hh, fb, fi);
            }
        }
    }

    // ---- pair merge: lane <-> lane^32 (two 16-row halves of same token) ----
    {
        float sb[4]; int si[4];
        #pragma unroll
        for (int c = 0; c < 4; ++c) { sb[c] = __shfl_xor(fb[c], 32); si[c] = __shfl_xor(fi[c], 32); }
        #pragma unroll
        for (int c = 0; c < 4; ++c) top4_insert(sb[c], si[c], fb, fi);
    }

    // ---- publish per-wave top-4, merge across code quarters (top-8) ----
    __syncthreads();                    // all LDS x reads done; reuse region
    float* candm = (float*)lds;                 // 1024 floats  [qc][tok][4]
    int*   candi = (int*)(lds + 4096);          // 1024 ints
    int*   wlCnt = (int*)(lds + 8192);
    int*   wlTok = (int*)(lds + 8208);          // 64 ints
    int*   wlGi  = (int*)(lds + 8464);          // 64*8 ints
    float* wlG   = (float*)(lds + 10512);       // 64*8 floats
    int*   bkArr = (int*)(lds + BK_OFF);        // 64 ints
    if (lane < 32) {
        const int slot = (qc * 64 + mt * 32 + lane) * 4;
        #pragma unroll
        for (int c = 0; c < 4; ++c) { candm[slot + c] = fb[c]; candi[slot + c] = fi[c]; }
    }
    if (tid == 0) *wlCnt = 0;
    __syncthreads();

    if (tid < TPB) {
        float g[8]; int gi[8];
        #pragma unroll
        for (int c = 0; c < 8; ++c) { g[c] = -FLT_MAX; gi[c] = KCODES; }
        #pragma unroll
        for (int q4 = 0; q4 < 4; ++q4) {
            const int slot = (q4 * 64 + tid) * 4;
            #pragma unroll
            for (int c = 0; c < 4; ++c) top8_insert(candm[slot + c], candi[slot + c], g, gi);
        }
        if (g[0] - g[1] > MARGIN) {
            // gap >> 2-term error window: argmax final
            out[tbase + tid] = (float)gi[0];
            bkArr[tid] = gi[0];
        } else {
            const int slot = atomicAdd(wlCnt, 1);
            wlTok[slot] = tid;
            #pragma unroll
            for (int c = 0; c < 8; ++c) { wlGi[slot * 8 + c] = gi[c]; wlG[slot * 8 + c] = g[c]; }
        }
    }
    __syncthreads();

    // ---- adjudication: all 8 waves round-robin the worklist; one wave/item ----
    {
        const int nIt = *wlCnt;
        for (int it = wv; it < nIt; it += 8) {
            const int tok = wlTok[it];
            const float g0 = wlG[it * 8];
            const float* xa = zb + tok;

            // xsq: bitwise np pairwise. Lane s<16 (s = h*8+j) runs stripe j of
            // half h as a serial 16-term fold; butterfly reproduces the exact
            // pairwise combine ((r0+r1)+(r2+r3))+((r4+r5)+(r6+r7)), sh0+sh1.
            float xsq;
            {
                const int h2 = (lane >> 3) & 1, j2 = lane & 7;
                float v[16];
                if (lane < 16) {
                    #pragma unroll
                    for (int i = 0; i < 16; ++i)
                        v[i] = xa[(size_t)(h2 * 128 + i * 8 + j2) * HWSZ];
                } else {
                    #pragma unroll
                    for (int i = 0; i < 16; ++i) v[i] = 0.f;
                }
                float rr;
                {
#pragma clang fp contract(off)
                    rr = v[0] * v[0];
                    #pragma unroll
                    for (int i = 1; i < 16; ++i) { float sq = v[i] * v[i]; rr = rr + sq; }
                }
                float t = rr;
                t = t + __shfl_xor(t, 1);
                t = t + __shfl_xor(t, 2);
                t = t + __shfl_xor(t, 4);
                t = t + __shfl_xor(t, 8);
                xsq = __shfl(t, 0);
            }

            // x column into regs for the dots (lane d0 = lane, +64 strides)
            double xv[4];
            #pragma unroll
            for (int i = 0; i < 4; ++i)
                xv[i] = (double)xa[(size_t)(lane + 64 * i) * HWSZ];

            float bestd = FLT_MAX; int bestk = KCODES;
            for (int c = 0; c < 8; ++c) {
                const float gc = wlG[it * 8 + c];
                if (c > 0 && g0 - gc > MARGIN) break;   // wave-uniform
                const int idx = wlGi[it * 8 + c];
                const float* wr = cb + (size_t)idx * DDIM;
                double A = 0.0;
                #pragma unroll
                for (int i = 0; i < 4; ++i)
                    A = fma((double)wr[lane + 64 * i], xv[i], A);
                // fp64 butterfly reduce (order-free: 29 spare bits vs fp32)
                A = A + __shfl_xor(A, 1);
                A = A + __shfl_xor(A, 2);
                A = A + __shfl_xor(A, 4);
                A = A + __shfl_xor(A, 8);
                A = A + __shfl_xor(A, 16);
                A = A + __shfl_xor(A, 32);
                float dist;
                {
#pragma clang fp contract(off)
                    const float xw = (float)A;
                    const float t1 = xsq - 2.0f * xw;
                    dist = t1 + wsq[idx];
                }
                if (dist < bestd || (dist == bestd && idx < bestk)) { bestd = dist; bestk = idx; }
            }
            if (lane == 0) {
                out[tbase + tok] = (float)bestk;
                bkArr[tok] = bestk;
            }
        }
    }

    // ---- z_q: 2 rounds of (stage 64 rows x 128 dims -> write coalesced) ----
    #pragma unroll
    for (int r = 0; r < 2; ++r) {
        __syncthreads();                // reuse region free / prev round done
        {
            #pragma unroll
            for (int rr = 0; rr < 8; ++rr) {
                const int row = wv * 8 + rr;
                const int bk = bkArr[row];                        // wave-uniform
                const float2 vv = *(const float2*)(cb + (size_t)bk * DDIM + r * 128 + lane * 2);
                *(float2*)(lds + row * ZQ_PITCH + lane * 8) = vv;
            }
        }
        __syncthreads();
        {
            const int tk = tid & 63, s = tid >> 6;     // s = 0..7, 16 dims each
            float* zq = out + TTOK + (size_t)n * (DDIM * HWSZ) + hw0 + tk;
            #pragma unroll
            for (int i = 0; i < 16; i += 4) {
                const f32x4 v = *(const f32x4*)(lds + tk * ZQ_PITCH + (s * 16 + i) * 4);
                #pragma unroll
                for (int j = 0; j < 4; ++j)
                    zq[(size_t)(r * 128 + s * 16 + i + j) * HWSZ] = v[j];
            }
        }
    }
}

// --------------------------------------------------------------- launch ----
extern "C" void kernel_launch(void* const* d_in, const int* in_sizes, int n_in,
                              void* d_out, int out_size, void* d_ws, size_t ws_size,
                              hipStream_t stream) {
    const float* z_e = (const float*)d_in[0];
    const float* cb  = (const float*)d_in[1];
    float* out = (float*)d_out;
    float* wsq = (float*)d_ws;                              // 2 KiB
    unsigned char* wsw = (unsigned char*)d_ws + 2048;       // 512 KiB fragment-packed w

    vq_prep<<<64, 256, 0, stream>>>(cb, wsw, wsq);
    vq_main<<<NBLK, 512, 0, stream>>>(z_e, cb, wsq, wsw, out);
}